// Round 1
// 2264.637 us; speedup vs baseline: 2.4934x; 2.4934x over previous
//
#include <hip/hip_runtime.h>
#include <hip/hip_bf16.h>
#include <stdint.h>

typedef unsigned short u16;   // bf16 bit pattern (internal scratch only)

#define B_    8
#define CIN_  64
#define COUT_ 128
#define C2_   256
#define H_    256
#define W_    256
#define HW_   (H_*W_)
#define EPS_  1e-5f

typedef __attribute__((ext_vector_type(8))) short bf16x8;
typedef __attribute__((ext_vector_type(4))) float f32x4;

// ---- static device scratch: zero-initialized at module load, not harness-poisoned ----
__device__ __align__(16) u16  g_R0[67108864];   // y1 raw, then g2 raw   (128 MiB)
__device__ __align__(16) u16  g_R1[67108864];   // g1 raw, then g3 raw   (128 MiB)
__device__ float g_wTa[8192];                   // w_c^T  [ci][co] 64x128
__device__ float g_wT1[32768];                  // w1^T   [ci][co] 128x256
__device__ float g_wT3[32768];                  // w3^T   [ci][co] 256x128
__device__ float g_stat[4096];                  // sums/ss/scale/shift, zeroed per launch
// conv2 MFMA: packed bf16 weights (BN1-folded, hi/lo split) in fragment-lane order
//   idx = (((ks72*2 + part)*16 + ntg)*64 + lane)*8 + j
//   k = tap*256 + ci ; ks72 = k>>5 ; lane = (k&31)>>3 *16 + (co&15) ; j = k&7 ; ntg = co>>4
__device__ __align__(16) u16 g_w2pk[1179648];   // 72*2*16*64*8 = 2.25 MiB
__device__ float g_S2[2304];                    // per-tap shift dot: S[tap*256+co]
__device__ float g_bias2p[16384];               // per-pixel bias [px][co] 64x256

// stat layout (float offsets)
#define S_SUMA 0
#define S_SSA  128
#define S_SUM1 256
#define S_SS1  512
#define S_SUM2 768
#define S_SS2  1024
#define S_SUM3 1280
#define S_SS3  1408
#define S_SCA  1536
#define S_SHA  1664
#define S_SC1  1792
#define S_SH1  2048
#define S_SC2  2304
#define S_SH2  2560
#define S_SC3  2816
#define S_SH3  2944

__device__ __forceinline__ float u2f(u16 u){
    unsigned int x = ((unsigned int)u) << 16; float f; __builtin_memcpy(&f, &x, 4); return f;
}
__device__ __forceinline__ u16 f2u(float f){
    __hip_bfloat16 h = __float2bfloat16(f); u16 u; __builtin_memcpy(&u, &h, 2); return u;
}

// ---------------- zero stats ----------------
__global__ void k_zero(){
    int i = blockIdx.x*blockDim.x + threadIdx.x;
    if (i < 4096) g_stat[i] = 0.f;
}

// ---------------- transpose 1x1 conv weights (fp32 in, fp32 out) ----------------
__global__ void k_prep_weights(const float* __restrict__ w_c, const float* __restrict__ w1,
                               const float* __restrict__ w3){
    int i = blockIdx.x*blockDim.x + threadIdx.x;
    if (i < 8192){ int ci = i >> 7, co = i & 127; g_wTa[i] = w_c[co*64 + ci]; return; }
    i -= 8192;
    if (i < 32768){ int ci = i >> 8, co = i & 255; g_wT1[i] = w1[co*128 + ci]; return; }
    i -= 32768;
    if (i < 32768){ int ci = i >> 7, co = i & 127; g_wT3[i] = w3[co*256 + ci]; }
}

// ---------------- stage A: 1x1 conv 64->128 + bias + relu -> g_R0 raw (bf16) ------------
__global__ __launch_bounds__(256) void k_convA(const float* __restrict__ x,
                                               const float* __restrict__ bias){
    __shared__ float sIn[64*64];
    int tile = blockIdx.x;
    int n   = tile >> 10;
    int hw0 = (tile & 1023) << 6;
    for (int s = threadIdx.x; s < 64*64; s += 256){
        int ci = s >> 6, px = s & 63;
        sIn[s] = x[(size_t)(n*CIN_ + ci)*HW_ + hw0 + px];
    }
    __syncthreads();
    int lane = threadIdx.x & 63;
    int wv   = __builtin_amdgcn_readfirstlane(threadIdx.x >> 6);
    int co_base = blockIdx.y*64 + wv*16;
    float acc[16];
    #pragma unroll
    for (int k = 0; k < 16; k++) acc[k] = 0.f;
    for (int ci = 0; ci < 64; ci++){
        float xv = sIn[ci*64 + lane];
        const float* wrow = g_wTa + ci*COUT_ + co_base;   // wave-uniform
        #pragma unroll
        for (int k = 0; k < 16; k++) acc[k] = fmaf(xv, wrow[k], acc[k]);
    }
    #pragma unroll
    for (int k = 0; k < 16; k++){
        int co = co_base + k;
        float v = fmaxf(acc[k] + bias[co], 0.f);
        g_R0[(size_t)(n*COUT_ + co)*HW_ + hw0 + lane] = f2u(v);
    }
}

// ---------------- per-channel sum/sumsq over (NOuter, C, S); which: 0=g_R0 1=g_R1 ----
__global__ __launch_bounds__(256) void k_stats(int which, int NOuter, int C, int S, int slices,
                                               int sumOff, int ssOff){
    const u16* buf = which ? g_R1 : g_R0;
    int c  = blockIdx.x / slices;
    int sl = blockIdx.x % slices;
    int nCnt = (NOuter - sl + slices - 1) / slices;
    long long per = (long long)nCnt * S;
    float s0 = 0.f, s1 = 0.f;
    for (long long j = threadIdx.x; j < per; j += 256){
        int nloc = (int)(j / S);
        int s    = (int)(j % S);
        int n    = sl + nloc*slices;
        float v  = u2f(buf[((size_t)n*C + c)*S + s]);
        s0 += v; s1 += v*v;
    }
    __shared__ float r0[256], r1[256];
    r0[threadIdx.x] = s0; r1[threadIdx.x] = s1;
    __syncthreads();
    for (int off = 128; off > 0; off >>= 1){
        if ((int)threadIdx.x < off){
            r0[threadIdx.x] += r0[threadIdx.x + off];
            r1[threadIdx.x] += r1[threadIdx.x + off];
        }
        __syncthreads();
    }
    if (threadIdx.x == 0){
        atomicAdd(&g_stat[sumOff + c], r0[0]);
        atomicAdd(&g_stat[ssOff  + c], r1[0]);
    }
}

// ---------------- per-channel BN affine params ----------------
__global__ void k_params(int sumOff, int ssOff, int scOff, int shOff,
                         const float* __restrict__ gamma, const float* __restrict__ beta,
                         float invN, int C){
    int c = blockIdx.x*blockDim.x + threadIdx.x;
    if (c >= C) return;
    float m   = g_stat[sumOff + c]*invN;
    float var = fmaxf(g_stat[ssOff + c]*invN - m*m, 0.f);
    float sc  = gamma[c] / sqrtf(var + EPS_);
    g_stat[scOff + c] = sc;
    g_stat[shOff + c] = beta[c] - m*sc;
}

// ---------------- apply BN-A: g_R0 raw -> d_out (fp32 full image) ----------------
__global__ __launch_bounds__(256) void k_apply_bn(float* __restrict__ out){
    size_t i = (size_t)blockIdx.x*256 + threadIdx.x;   // 67,108,864 total
    int c = (int)((i >> 16) & 127);
    out[i] = g_stat[S_SCA + c]*u2f(g_R0[i]) + g_stat[S_SHA + c];
}

// ---------------- stage 1: gather + 1x1 conv 128->256 + relu -> g_R1 raw ----------------
__global__ __launch_bounds__(256) void k_conv1(const float* __restrict__ xin,
                                               const int* __restrict__ abi,
                                               const float* __restrict__ bias){
    __shared__ float sIn[128*64];
    int b  = blockIdx.x;
    int n  = abi[b*3+0], by = abi[b*3+1], bx = abi[b*3+2];
    const float* base = xin + (size_t)n*COUT_*HW_ + by*8*W_ + bx*8;
    for (int s = threadIdx.x; s < 128*64; s += 256){
        int ci = s >> 6, px = s & 63, r = px >> 3, cc = px & 7;
        sIn[s] = base[(size_t)ci*HW_ + r*W_ + cc];
    }
    __syncthreads();
    int lane = threadIdx.x & 63;
    int wv   = __builtin_amdgcn_readfirstlane(threadIdx.x >> 6);
    int co_base = blockIdx.y*64 + wv*16;
    float acc[16];
    #pragma unroll
    for (int k = 0; k < 16; k++) acc[k] = 0.f;
    for (int ci = 0; ci < 128; ci++){
        float xv = sIn[ci*64 + lane];
        const float* wrow = g_wT1 + ci*C2_ + co_base;
        #pragma unroll
        for (int k = 0; k < 16; k++) acc[k] = fmaf(xv, wrow[k], acc[k]);
    }
    #pragma unroll
    for (int k = 0; k < 16; k++){
        int co = co_base + k;
        float v = fmaxf(acc[k] + bias[co], 0.f);
        g_R1[((size_t)b*C2_ + co)*64 + lane] = f2u(v);
    }
}

// ---------------- conv2 weight prep: W' = W2*sc1, hi/lo bf16 split, fragment-packed ----
__global__ __launch_bounds__(256) void k_prep_w2(const float* __restrict__ w2){
    int id = blockIdx.x*256 + threadIdx.x;     // 589824 = 2304 k * 256 co
    if (id >= 589824) return;
    int co  = id & 255;
    int k   = id >> 8;          // k = tap*256 + ci
    int tap = k >> 8;
    int ci  = k & 255;
    float wv = w2[((size_t)co*256 + ci)*9 + tap] * g_stat[S_SC1 + ci];
    u16 hi = f2u(wv);
    u16 lo = f2u(wv - u2f(hi));
    int ks72  = k >> 5;
    int kin   = k & 31;
    int lanew = (kin >> 3)*16 + (co & 15);
    int j     = kin & 7;
    int ntg   = co >> 4;
    size_t i0 = ((size_t)(ks72*32 + ntg)*64 + lanew)*8 + j;   // part 0 (hi)
    g_w2pk[i0]        = hi;
    g_w2pk[i0 + 8192] = lo;                                   // part 1 (+16 nt slots)
}

// per-tap shift dot products: S[tap][co] = sum_ci W2[co,ci,tap]*sh1[ci]
__global__ __launch_bounds__(256) void k_prep_S2(const float* __restrict__ w2){
    int tc  = blockIdx.x;       // tap*256 + co
    int tap = tc >> 8, co = tc & 255;
    int ci  = threadIdx.x;
    float v = w2[((size_t)co*256 + ci)*9 + tap] * g_stat[S_SH1 + ci];
    __shared__ float r[256];
    r[ci] = v; __syncthreads();
    for (int off = 128; off > 0; off >>= 1){
        if (ci < off) r[ci] += r[ci + off];
        __syncthreads();
    }
    if (ci == 0) g_S2[tc] = r[0];
}

// per-pixel conv2 bias: b2[co] + sum over taps whose input pixel is inside the block
__global__ void k_prep_bias2(const float* __restrict__ b2){
    int px = blockIdx.x;        // 64
    int co = threadIdx.x;       // 256
    int rr = px >> 3, cc = px & 7;
    float s = b2[co];
    for (int tap = 0; tap < 9; tap++){
        int dr = tap/3, dc = tap - 3*(tap/3);
        int r2 = rr + dr, c2 = cc + dc;     // padded coords; data iff 1..8
        if (r2 >= 1 && r2 <= 8 && c2 >= 1 && c2 <= 8) s += g_S2[tap*256 + co];
    }
    g_bias2p[px*256 + co] = s;
}

// ---------------- stage 2: 3x3 conv 256->256 via MFMA (BN-1 folded into weights) -------
// A = raw bf16 activations (exact), zero-padded [10][10][256] in LDS, XOR-swizzled.
// B = g_w2pk fragments straight from global (L2-resident).
// out: relu(conv+bias2p) -> g_R0 raw bf16.
__global__ __launch_bounds__(256, 2) void k_conv2m(){
    __shared__ __align__(1024) u16 sA[25600];   // 10*10*256 bf16, swizzled
    char* sB = (char*)sA;
    int b = blockIdx.x;

    // ---- zero the 36 border cells (16B segments) ----
    for (int s = threadIdx.x; s < 36*32; s += 256){
        int cell = s >> 5, seg = s & 31;     // seg*8 = ci0
        int L;
        if      (cell < 10) L = cell;
        else if (cell < 20) L = 90 + (cell - 10);
        else if (cell < 28) L = (cell - 19)*10;
        else                L = (cell - 27)*10 + 9;
        int off = (L*512 + seg*16) ^ ((L & 7) << 4);
        uint4 z = {0u,0u,0u,0u};
        *(uint4*)(sB + off) = z;
    }
    // ---- interior: transpose [ci][px] -> padded [L][ci], 4ci x 4px micro-tiles ----
    const u16* src = g_R1 + (size_t)b*C2_*64;
    for (int q = threadIdx.x; q < 1024; q += 256){
        int px0 = (q & 15)*4;
        int ci0 = (q >> 4)*4;
        ushort4 v0 = *(const ushort4*)(src + (ci0+0)*64 + px0);
        ushort4 v1 = *(const ushort4*)(src + (ci0+1)*64 + px0);
        ushort4 v2 = *(const ushort4*)(src + (ci0+2)*64 + px0);
        ushort4 v3 = *(const ushort4*)(src + (ci0+3)*64 + px0);
        #pragma unroll
        for (int i = 0; i < 4; i++){
            int px = px0 + i;
            int L  = ((px >> 3) + 1)*10 + (px & 7) + 1;
            int off = (L*512 + ci0*2) ^ ((L & 7) << 4);
            ushort4 w;
            w.x = (&v0.x)[i]; w.y = (&v1.x)[i]; w.z = (&v2.x)[i]; w.w = (&v3.x)[i];
            *(ushort4*)(sB + off) = w;
        }
    }
    __syncthreads();

    int lane = threadIdx.x & 63;
    int wv   = __builtin_amdgcn_readfirstlane(threadIdx.x >> 6);
    int l15  = lane & 15;
    int lg   = lane >> 4;          // 0..3 : k-octet group / acc row group
    int rA   = l15 >> 3;           // A-row (px) components: px = m0*16 + l15
    int cA   = l15 & 7;

    f32x4 acc[4][4];
    #pragma unroll
    for (int m0 = 0; m0 < 4; m0++)
        #pragma unroll
        for (int nt = 0; nt < 4; nt++)
            acc[m0][nt] = (f32x4){0.f,0.f,0.f,0.f};

    for (int tap = 0; tap < 9; tap++){
        int dr = tap/3, dc = tap - 3*(tap/3);
        #pragma unroll
        for (int ks = 0; ks < 8; ks++){
            int ks72 = tap*8 + ks;
            const u16* bp = g_w2pk + (size_t)(ks72*32)*512;   // *16 nt *64 lane *8 j /2... = 32*512 u16 per ks72
            bf16x8 bh[4], bl[4];
            #pragma unroll
            for (int nt = 0; nt < 4; nt++){
                int ntg = wv*4 + nt;
                bh[nt] = *(const bf16x8*)(bp + ((size_t)ntg*64 + lane)*8);
                bl[nt] = *(const bf16x8*)(bp + ((size_t)(16 + ntg)*64 + lane)*8);
            }
            bf16x8 af[4];
            #pragma unroll
            for (int m0 = 0; m0 < 4; m0++){
                int L   = (m0*2 + rA + dr)*10 + cA + dc;
                int off = (L*512 + ks*64 + lg*16) ^ ((L & 7) << 4);
                af[m0]  = *(const bf16x8*)(sB + off);
            }
            #pragma unroll
            for (int m0 = 0; m0 < 4; m0++){
                #pragma unroll
                for (int nt = 0; nt < 4; nt++){
                    acc[m0][nt] = __builtin_amdgcn_mfma_f32_16x16x32_bf16(af[m0], bh[nt], acc[m0][nt], 0, 0, 0);
                    acc[m0][nt] = __builtin_amdgcn_mfma_f32_16x16x32_bf16(af[m0], bl[nt], acc[m0][nt], 0, 0, 0);
                }
            }
        }
    }

    // ---- epilogue: + per-pixel bias, relu, pack bf16, store [co][px] ----
    u16* dst = g_R0 + (size_t)b*C2_*64;
    #pragma unroll
    for (int m0 = 0; m0 < 4; m0++){
        int px0 = m0*16 + lg*4;
        #pragma unroll
        for (int nt = 0; nt < 4; nt++){
            int co = wv*64 + nt*16 + l15;
            float f0 = fmaxf(acc[m0][nt][0] + g_bias2p[(px0+0)*256 + co], 0.f);
            float f1 = fmaxf(acc[m0][nt][1] + g_bias2p[(px0+1)*256 + co], 0.f);
            float f2 = fmaxf(acc[m0][nt][2] + g_bias2p[(px0+2)*256 + co], 0.f);
            float f3 = fmaxf(acc[m0][nt][3] + g_bias2p[(px0+3)*256 + co], 0.f);
            uint2 o;
            o.x = (unsigned)f2u(f0) | ((unsigned)f2u(f1) << 16);
            o.y = (unsigned)f2u(f2) | ((unsigned)f2u(f3) << 16);
            *(uint2*)(dst + (size_t)co*64 + px0) = o;
        }
    }
}

// ---------------- stage 3: 1x1 conv 256->128 (BN-2 folded) -> g_R1 raw ----------------
__global__ __launch_bounds__(256) void k_conv3(const float* __restrict__ bias){
    __shared__ float sIn[128*64];
    int b    = blockIdx.x;
    int lane = threadIdx.x & 63;
    int wv   = __builtin_amdgcn_readfirstlane(threadIdx.x >> 6);
    int co_base = blockIdx.y*64 + wv*16;
    float acc[16];
    #pragma unroll
    for (int k = 0; k < 16; k++) acc[k] = 0.f;
    for (int cic = 0; cic < 2; cic++){
        for (int s = threadIdx.x; s < 128*64; s += 256){
            int ci = s >> 6, px = s & 63;
            int ciG = cic*128 + ci;
            float raw = u2f(g_R0[((size_t)b*C2_ + ciG)*64 + px]);
            sIn[s] = g_stat[S_SC2 + ciG]*raw + g_stat[S_SH2 + ciG];
        }
        __syncthreads();
        for (int ci = 0; ci < 128; ci++){
            float xv = sIn[ci*64 + lane];
            const float* wrow = g_wT3 + (cic*128 + ci)*COUT_ + co_base;
            #pragma unroll
            for (int k = 0; k < 16; k++) acc[k] = fmaf(xv, wrow[k], acc[k]);
        }
        __syncthreads();
    }
    #pragma unroll
    for (int k = 0; k < 16; k++){
        int co = co_base + k;
        float v = fmaxf(acc[k] + bias[co], 0.f);
        g_R1[((size_t)b*COUT_ + co)*64 + lane] = f2u(v);
    }
}

// ---------------- scatter: BN-3 + write active blocks into d_out (fp32) ----------------
__global__ __launch_bounds__(256) void k_scatter(const int* __restrict__ abi,
                                                 float* __restrict__ out){
    int b  = blockIdx.x;
    int n  = abi[b*3+0], by = abi[b*3+1], bx = abi[b*3+2];
    float* base = out + (size_t)n*COUT_*HW_ + by*8*W_ + bx*8;
    for (int s = threadIdx.x; s < COUT_*64; s += 256){
        int co = s >> 6, px = s & 63, r = px >> 3, cc = px & 7;
        float v = g_stat[S_SC3 + co]*u2f(g_R1[(size_t)b*COUT_*64 + s]) + g_stat[S_SH3 + co];
        base[(size_t)co*HW_ + r*W_ + cc] = v;
    }
}

extern "C" void kernel_launch(void* const* d_in, const int* in_sizes, int n_in,
                              void* d_out, int out_size, void* d_ws, size_t ws_size,
                              hipStream_t stream){
    const float* x    = (const float*)d_in[0];
    const int*   abi  = (const int*)  d_in[1];
    const float* w_c  = (const float*)d_in[2];
    const float* b_c  = (const float*)d_in[3];
    const float* ga_c = (const float*)d_in[4];
    const float* be_c = (const float*)d_in[5];
    const float* w1   = (const float*)d_in[6];
    const float* b1   = (const float*)d_in[7];
    const float* ga1  = (const float*)d_in[8];
    const float* be1  = (const float*)d_in[9];
    const float* w2   = (const float*)d_in[10];
    const float* b2   = (const float*)d_in[11];
    const float* ga2  = (const float*)d_in[12];
    const float* be2  = (const float*)d_in[13];
    const float* w3   = (const float*)d_in[14];
    const float* b3   = (const float*)d_in[15];
    const float* ga3  = (const float*)d_in[16];
    const float* be3  = (const float*)d_in[17];
    int NB = in_sizes[1] / 3;              // 4096 active blocks
    (void)d_ws; (void)ws_size; (void)n_in; (void)out_size;

    k_zero<<<16, 256, 0, stream>>>();
    k_prep_weights<<<288, 256, 0, stream>>>(w_c, w1, w3);

    // stage A: conv -> raw (g_R0), stats, params, apply -> d_out (fp32)
    k_convA<<<dim3(8192, 2), 256, 0, stream>>>(x, b_c);
    k_stats<<<128*8, 256, 0, stream>>>(0, 8, 128, 65536, 8, S_SUMA, S_SSA);
    k_params<<<1, 128, 0, stream>>>(S_SUMA, S_SSA, S_SCA, S_SHA, ga_c, be_c, 1.f/(8.f*65536.f), 128);
    k_apply_bn<<<262144, 256, 0, stream>>>((float*)d_out);

    // stage 1: gather + conv1 -> raw (g_R1), stats, params
    k_conv1<<<dim3(NB, 4), 256, 0, stream>>>((const float*)d_out, abi, b1);
    k_stats<<<256*32, 256, 0, stream>>>(1, NB, 256, 64, 32, S_SUM1, S_SS1);
    k_params<<<1, 256, 0, stream>>>(S_SUM1, S_SS1, S_SC1, S_SH1, ga1, be1, 1.f/((float)NB*64.f), 256);

    // conv2 weight/bias prep (needs sc1/sh1)
    k_prep_w2<<<2304, 256, 0, stream>>>(w2);
    k_prep_S2<<<2304, 256, 0, stream>>>(w2);
    k_prep_bias2<<<64, 256, 0, stream>>>(b2);

    // stage 2: 3x3 conv via MFMA -> raw (g_R0), stats, params
    k_conv2m<<<NB, 256, 0, stream>>>();
    k_stats<<<256*32, 256, 0, stream>>>(0, NB, 256, 64, 32, S_SUM2, S_SS2);
    k_params<<<1, 256, 0, stream>>>(S_SUM2, S_SS2, S_SC2, S_SH2, ga2, be2, 1.f/((float)NB*64.f), 256);

    // stage 3: 1x1 conv (BN-2 folded) -> raw (g_R1), stats, params
    k_conv3<<<dim3(NB, 2), 256, 0, stream>>>(b3);
    k_stats<<<128*32, 256, 0, stream>>>(1, NB, 128, 64, 32, S_SUM3, S_SS3);
    k_params<<<1, 128, 0, stream>>>(S_SUM3, S_SS3, S_SC3, S_SH3, ga3, be3, 1.f/((float)NB*64.f), 128);

    // scatter with BN-3
    k_scatter<<<NB, 256, 0, stream>>>(abi, (float*)d_out);
}

// Round 2
// 1478.362 us; speedup vs baseline: 3.8195x; 1.5319x over previous
//
#include <hip/hip_runtime.h>
#include <hip/hip_bf16.h>
#include <stdint.h>

typedef unsigned short u16;   // bf16 bit pattern (internal scratch only)

#define B_    8
#define CIN_  64
#define COUT_ 128
#define C2_   256
#define H_    256
#define W_    256
#define HW_   (H_*W_)
#define EPS_  1e-5f

typedef __attribute__((ext_vector_type(8))) short bf16x8;
typedef __attribute__((ext_vector_type(4))) float f32x4;

// ---- static device scratch: zero-initialized at module load, not harness-poisoned ----
__device__ __align__(16) u16  g_R0[67108864];   // y1 raw, then g2 raw   (128 MiB)
__device__ __align__(16) u16  g_R1[67108864];   // g1 raw, then g3 raw   (128 MiB)
__device__ float g_wTa[8192];                   // w_c^T  [ci][co] 64x128
__device__ float g_stat[4096];                  // sums/ss/scale/shift, zeroed per launch
// conv2 MFMA: packed bf16 weights (BN1-folded, hi/lo split) in fragment-lane order
//   k = tap*256 + ci ; ks72 = k>>5 ; lane = (k&31)>>3*16 + (co&15) ; j = k&7 ; ntg = co>>4
__device__ __align__(16) u16 g_w2pk[1179648];   // 72 ks * (16 hi + 16 lo) * 64 * 8
__device__ float g_S2[2304];                    // per-tap shift dot: S[tap*256+co]
__device__ float g_bias2p[16384];               // per-pixel bias [px][co] 64x256
// conv1 MFMA: W1' = W1*scA hi/lo pack (K=128, N=256): 4 ks * (16 hi + 16 lo) * 64 * 8
__device__ __align__(16) u16 g_w1pk[65536];
__device__ float g_bias1p[256];                 // b1 + W1·shA
// conv3 MFMA: W3' = W3*sc2 hi/lo pack (K=256, N=128): 8 ks * (8 hi + 8 lo) * 64 * 8
__device__ __align__(16) u16 g_w3pk[65536];
__device__ float g_bias3p[128];                 // b3 + W3·sh2

// stat layout (float offsets)
#define S_SUMA 0
#define S_SSA  128
#define S_SUM1 256
#define S_SS1  512
#define S_SUM2 768
#define S_SS2  1024
#define S_SUM3 1280
#define S_SS3  1408
#define S_SCA  1536
#define S_SHA  1664
#define S_SC1  1792
#define S_SH1  2048
#define S_SC2  2304
#define S_SH2  2560
#define S_SC3  2816
#define S_SH3  2944

__device__ __forceinline__ float u2f(u16 u){
    unsigned int x = ((unsigned int)u) << 16; float f; __builtin_memcpy(&f, &x, 4); return f;
}
__device__ __forceinline__ u16 f2u(float f){
    __hip_bfloat16 h = __float2bfloat16(f); u16 u; __builtin_memcpy(&u, &h, 2); return u;
}
__device__ __forceinline__ float bitsf(unsigned int x){ float f; __builtin_memcpy(&f, &x, 4); return f; }

// ---------------- zero stats ----------------
__global__ void k_zero(){
    int i = blockIdx.x*blockDim.x + threadIdx.x;
    if (i < 4096) g_stat[i] = 0.f;
}

// ---------------- transpose w_c (fp32) ----------------
__global__ void k_prep_weights(const float* __restrict__ w_c){
    int i = blockIdx.x*blockDim.x + threadIdx.x;
    if (i < 8192){ int ci = i >> 7, co = i & 127; g_wTa[i] = w_c[co*64 + ci]; }
}

// ---------------- stage A: 1x1 conv 64->128 + bias + relu -> g_R0 raw (bf16) ------------
__global__ __launch_bounds__(256) void k_convA(const float* __restrict__ x,
                                               const float* __restrict__ bias){
    __shared__ float sIn[64*64];
    int tile = blockIdx.x;
    int n   = tile >> 10;
    int hw0 = (tile & 1023) << 6;
    for (int s = threadIdx.x; s < 64*64; s += 256){
        int ci = s >> 6, px = s & 63;
        sIn[s] = x[(size_t)(n*CIN_ + ci)*HW_ + hw0 + px];
    }
    __syncthreads();
    int lane = threadIdx.x & 63;
    int wv   = __builtin_amdgcn_readfirstlane(threadIdx.x >> 6);
    int co_base = blockIdx.y*64 + wv*16;
    float acc[16];
    #pragma unroll
    for (int k = 0; k < 16; k++) acc[k] = 0.f;
    for (int ci = 0; ci < 64; ci++){
        float xv = sIn[ci*64 + lane];
        const float* wrow = g_wTa + ci*COUT_ + co_base;   // wave-uniform
        #pragma unroll
        for (int k = 0; k < 16; k++) acc[k] = fmaf(xv, wrow[k], acc[k]);
    }
    #pragma unroll
    for (int k = 0; k < 16; k++){
        int co = co_base + k;
        float v = fmaxf(acc[k] + bias[co], 0.f);
        g_R0[(size_t)(n*COUT_ + co)*HW_ + hw0 + lane] = f2u(v);
    }
}

// ---------------- per-channel sum/sumsq over (NOuter, C, S); vectorized 8/thread -------
__global__ __launch_bounds__(256) void k_stats(int which, int NOuter, int C, int S, int slices,
                                               int sumOff, int ssOff){
    const u16* buf = which ? g_R1 : g_R0;
    int c  = blockIdx.x / slices;
    int sl = blockIdx.x % slices;
    int nCnt = (NOuter - sl + slices - 1) / slices;
    int S8 = S >> 3;
    long long per8 = (long long)nCnt * S8;
    float s0 = 0.f, s1 = 0.f;
    for (long long j = threadIdx.x; j < per8; j += 256){
        int nloc = (int)(j / S8);
        int s8   = (int)(j % S8);
        int n    = sl + nloc*slices;
        uint4 v = *(const uint4*)(buf + ((size_t)n*C + c)*S + s8*8);
        #pragma unroll
        for (int q = 0; q < 4; q++){
            unsigned u = (&v.x)[q];
            float a = bitsf(u << 16);
            float b = bitsf(u & 0xffff0000u);
            s0 += a + b; s1 += a*a + b*b;
        }
    }
    __shared__ float r0[256], r1[256];
    r0[threadIdx.x] = s0; r1[threadIdx.x] = s1;
    __syncthreads();
    for (int off = 128; off > 0; off >>= 1){
        if ((int)threadIdx.x < off){
            r0[threadIdx.x] += r0[threadIdx.x + off];
            r1[threadIdx.x] += r1[threadIdx.x + off];
        }
        __syncthreads();
    }
    if (threadIdx.x == 0){
        atomicAdd(&g_stat[sumOff + c], r0[0]);
        atomicAdd(&g_stat[ssOff  + c], r1[0]);
    }
}

// ---------------- per-channel BN affine params ----------------
__global__ void k_params(int sumOff, int ssOff, int scOff, int shOff,
                         const float* __restrict__ gamma, const float* __restrict__ beta,
                         float invN, int C){
    int c = blockIdx.x*blockDim.x + threadIdx.x;
    if (c >= C) return;
    float m   = g_stat[sumOff + c]*invN;
    float var = fmaxf(g_stat[ssOff + c]*invN - m*m, 0.f);
    float sc  = gamma[c] / sqrtf(var + EPS_);
    g_stat[scOff + c] = sc;
    g_stat[shOff + c] = beta[c] - m*sc;
}

// ---------------- apply BN-A: g_R0 raw -> d_out (fp32 full image), 8 elems/thread ------
__global__ __launch_bounds__(256) void k_apply_bn(float* __restrict__ out){
    size_t i8 = ((size_t)blockIdx.x*256 + threadIdx.x)*8;   // 67,108,864 total
    int c = (int)((i8 >> 16) & 127);
    float sc = g_stat[S_SCA + c], sh = g_stat[S_SHA + c];
    uint4 v = *(const uint4*)(g_R0 + i8);
    float4 o0, o1;
    o0.x = sc*bitsf(v.x << 16)       + sh;
    o0.y = sc*bitsf(v.x & 0xffff0000u) + sh;
    o0.z = sc*bitsf(v.y << 16)       + sh;
    o0.w = sc*bitsf(v.y & 0xffff0000u) + sh;
    o1.x = sc*bitsf(v.z << 16)       + sh;
    o1.y = sc*bitsf(v.z & 0xffff0000u) + sh;
    o1.z = sc*bitsf(v.w << 16)       + sh;
    o1.w = sc*bitsf(v.w & 0xffff0000u) + sh;
    *(float4*)(out + i8)     = o0;
    *(float4*)(out + i8 + 4) = o1;
}

// ---------------- conv1 weight prep: W1' = W1*scA, hi/lo, fragment-packed --------------
__global__ __launch_bounds__(256) void k_prep_w1p(const float* __restrict__ w1){
    int id = blockIdx.x*256 + threadIdx.x;     // 32768 = 128 ci * 256 co
    if (id >= 32768) return;
    int co = id & 255, ci = id >> 8;
    float wv = w1[co*128 + ci] * g_stat[S_SCA + ci];
    u16 hi = f2u(wv);
    u16 lo = f2u(wv - u2f(hi));
    int ks = ci >> 5, kin = ci & 31;
    int lanew = (kin >> 3)*16 + (co & 15);
    int j = kin & 7, ntg = co >> 4;
    size_t i0 = ((size_t)(ks*32 + ntg)*64 + lanew)*8 + j;
    g_w1pk[i0]        = hi;
    g_w1pk[i0 + 8192] = lo;
}
__global__ void k_prep_b1(const float* __restrict__ w1, const float* __restrict__ b1){
    int co = blockIdx.x;        // 256
    int ci = threadIdx.x;       // 128
    __shared__ float r[128];
    r[ci] = w1[co*128 + ci] * g_stat[S_SHA + ci];
    __syncthreads();
    for (int off = 64; off > 0; off >>= 1){
        if (ci < off) r[ci] += r[ci + off];
        __syncthreads();
    }
    if (ci == 0) g_bias1p[co] = b1[co] + r[0];
}

// ---------------- stage 1 MFMA: gather bf16 + 1x1 conv 128->256 (BN-A folded) ----------
__global__ __launch_bounds__(256) void k_conv1m(const int* __restrict__ abi){
    __shared__ __align__(1024) u16 sA[8192];   // [64px][128ci] bf16, swizzled (16 KiB)
    char* sB = (char*)sA;
    int b = blockIdx.x;
    int n = abi[b*3+0], by = abi[b*3+1], bx = abi[b*3+2];
    const u16* src = g_R0 + (size_t)n*COUT_*HW_ + (size_t)(by*8)*W_ + bx*8;
    for (int q = threadIdx.x; q < 512; q += 256){
        int ci0 = (q >> 4)*4;
        int rc  = q & 15;
        int r = rc >> 1, c0 = (rc & 1)*4;
        ushort4 v0 = *(const ushort4*)(src + (size_t)(ci0+0)*HW_ + r*W_ + c0);
        ushort4 v1 = *(const ushort4*)(src + (size_t)(ci0+1)*HW_ + r*W_ + c0);
        ushort4 v2 = *(const ushort4*)(src + (size_t)(ci0+2)*HW_ + r*W_ + c0);
        ushort4 v3 = *(const ushort4*)(src + (size_t)(ci0+3)*HW_ + r*W_ + c0);
        #pragma unroll
        for (int i = 0; i < 4; i++){
            int px  = r*8 + c0 + i;
            int off = (px*256 + ci0*2) ^ ((px & 7) << 4);
            ushort4 w;
            w.x = (&v0.x)[i]; w.y = (&v1.x)[i]; w.z = (&v2.x)[i]; w.w = (&v3.x)[i];
            *(ushort4*)(sB + off) = w;
        }
    }
    __syncthreads();
    int lane = threadIdx.x & 63;
    int wv   = __builtin_amdgcn_readfirstlane(threadIdx.x >> 6);
    int l15  = lane & 15, lg = lane >> 4;
    f32x4 acc[4][4];
    #pragma unroll
    for (int m0 = 0; m0 < 4; m0++)
        #pragma unroll
        for (int nt = 0; nt < 4; nt++) acc[m0][nt] = (f32x4){0.f,0.f,0.f,0.f};
    #pragma unroll
    for (int ks = 0; ks < 4; ks++){
        bf16x8 bh[4], bl[4];
        #pragma unroll
        for (int nt = 0; nt < 4; nt++){
            int ntg = wv*4 + nt;
            const u16* bp = g_w1pk + ((size_t)(ks*32 + ntg)*64 + lane)*8;
            bh[nt] = *(const bf16x8*)bp;
            bl[nt] = *(const bf16x8*)(bp + 8192);
        }
        bf16x8 af[4];
        #pragma unroll
        for (int m0 = 0; m0 < 4; m0++){
            int px  = m0*16 + l15;
            int off = (px*256 + ks*64 + lg*16) ^ ((px & 7) << 4);
            af[m0]  = *(const bf16x8*)(sB + off);
        }
        #pragma unroll
        for (int m0 = 0; m0 < 4; m0++)
            #pragma unroll
            for (int nt = 0; nt < 4; nt++){
                acc[m0][nt] = __builtin_amdgcn_mfma_f32_16x16x32_bf16(af[m0], bh[nt], acc[m0][nt], 0, 0, 0);
                acc[m0][nt] = __builtin_amdgcn_mfma_f32_16x16x32_bf16(af[m0], bl[nt], acc[m0][nt], 0, 0, 0);
            }
    }
    u16* dst = g_R1 + (size_t)b*C2_*64;
    #pragma unroll
    for (int m0 = 0; m0 < 4; m0++){
        int px0 = m0*16 + lg*4;
        #pragma unroll
        for (int nt = 0; nt < 4; nt++){
            int co = wv*64 + nt*16 + l15;
            float bb = g_bias1p[co];
            float f0 = fmaxf(acc[m0][nt][0] + bb, 0.f);
            float f1 = fmaxf(acc[m0][nt][1] + bb, 0.f);
            float f2 = fmaxf(acc[m0][nt][2] + bb, 0.f);
            float f3 = fmaxf(acc[m0][nt][3] + bb, 0.f);
            uint2 o;
            o.x = (unsigned)f2u(f0) | ((unsigned)f2u(f1) << 16);
            o.y = (unsigned)f2u(f2) | ((unsigned)f2u(f3) << 16);
            *(uint2*)(dst + (size_t)co*64 + px0) = o;
        }
    }
}

// ---------------- conv2 weight prep: W' = W2*sc1, hi/lo bf16 split, fragment-packed ----
__global__ __launch_bounds__(256) void k_prep_w2(const float* __restrict__ w2){
    int id = blockIdx.x*256 + threadIdx.x;     // 589824 = 2304 k * 256 co
    if (id >= 589824) return;
    int co  = id & 255;
    int k   = id >> 8;          // k = tap*256 + ci
    int tap = k >> 8;
    int ci  = k & 255;
    float wv = w2[((size_t)co*256 + ci)*9 + tap] * g_stat[S_SC1 + ci];
    u16 hi = f2u(wv);
    u16 lo = f2u(wv - u2f(hi));
    int ks72  = k >> 5;
    int kin   = k & 31;
    int lanew = (kin >> 3)*16 + (co & 15);
    int j     = kin & 7;
    int ntg   = co >> 4;
    size_t i0 = ((size_t)(ks72*32 + ntg)*64 + lanew)*8 + j;   // part 0 (hi)
    g_w2pk[i0]        = hi;
    g_w2pk[i0 + 8192] = lo;                                   // part 1 (+16 nt slots)
}

// per-tap shift dot products: S[tap][co] = sum_ci W2[co,ci,tap]*sh1[ci]
__global__ __launch_bounds__(256) void k_prep_S2(const float* __restrict__ w2){
    int tc  = blockIdx.x;       // tap*256 + co
    int tap = tc >> 8, co = tc & 255;
    int ci  = threadIdx.x;
    float v = w2[((size_t)co*256 + ci)*9 + tap] * g_stat[S_SH1 + ci];
    __shared__ float r[256];
    r[ci] = v; __syncthreads();
    for (int off = 128; off > 0; off >>= 1){
        if (ci < off) r[ci] += r[ci + off];
        __syncthreads();
    }
    if (ci == 0) g_S2[tc] = r[0];
}

// per-pixel conv2 bias: b2[co] + sum over taps whose input pixel is inside the block
__global__ void k_prep_bias2(const float* __restrict__ b2){
    int px = blockIdx.x;        // 64
    int co = threadIdx.x;       // 256
    int rr = px >> 3, cc = px & 7;
    float s = b2[co];
    for (int tap = 0; tap < 9; tap++){
        int dr = tap/3, dc = tap - 3*(tap/3);
        int r2 = rr + dr, c2 = cc + dc;     // padded coords; data iff 1..8
        if (r2 >= 1 && r2 <= 8 && c2 >= 1 && c2 <= 8) s += g_S2[tap*256 + co];
    }
    g_bias2p[px*256 + co] = s;
}

// ---------------- stage 2: 3x3 conv 256->256 via MFMA, TWO blocks per workgroup --------
// 8 waves: waves 0-3 -> block b0, waves 4-7 -> block b1 (same B addresses -> L1/L2 reuse)
__global__ __launch_bounds__(512, 2) void k_conv2m(int NB){
    __shared__ __align__(1024) u16 sA2[51200];  // 2 x (10*10*256) bf16, swizzled (100 KiB)
    int half = threadIdx.x >> 8;                // 0 or 1
    int tid  = threadIdx.x & 255;
    int b = blockIdx.x*2 + half;
    if (b >= NB) b = NB - 1;                    // NB always even here; safety only
    char* sB = (char*)sA2 + half*51200;

    // ---- zero the 36 border cells (16B segments) ----
    for (int s = tid; s < 36*32; s += 256){
        int cell = s >> 5, seg = s & 31;
        int L;
        if      (cell < 10) L = cell;
        else if (cell < 20) L = 90 + (cell - 10);
        else if (cell < 28) L = (cell - 19)*10;
        else                L = (cell - 27)*10 + 9;
        int off = (L*512 + seg*16) ^ ((L & 7) << 4);
        uint4 z = {0u,0u,0u,0u};
        *(uint4*)(sB + off) = z;
    }
    // ---- interior: transpose [ci][px] -> padded [L][ci], 4ci x 4px micro-tiles ----
    const u16* src = g_R1 + (size_t)b*C2_*64;
    for (int q = tid; q < 1024; q += 256){
        int px0 = (q & 15)*4;
        int ci0 = (q >> 4)*4;
        ushort4 v0 = *(const ushort4*)(src + (ci0+0)*64 + px0);
        ushort4 v1 = *(const ushort4*)(src + (ci0+1)*64 + px0);
        ushort4 v2 = *(const ushort4*)(src + (ci0+2)*64 + px0);
        ushort4 v3 = *(const ushort4*)(src + (ci0+3)*64 + px0);
        #pragma unroll
        for (int i = 0; i < 4; i++){
            int px = px0 + i;
            int L  = ((px >> 3) + 1)*10 + (px & 7) + 1;
            int off = (L*512 + ci0*2) ^ ((L & 7) << 4);
            ushort4 w;
            w.x = (&v0.x)[i]; w.y = (&v1.x)[i]; w.z = (&v2.x)[i]; w.w = (&v3.x)[i];
            *(ushort4*)(sB + off) = w;
        }
    }
    __syncthreads();

    int lane = threadIdx.x & 63;
    int wv   = __builtin_amdgcn_readfirstlane((threadIdx.x >> 6) & 3);
    int l15  = lane & 15;
    int lg   = lane >> 4;
    int rA   = l15 >> 3;
    int cA   = l15 & 7;

    f32x4 acc[4][4];
    #pragma unroll
    for (int m0 = 0; m0 < 4; m0++)
        #pragma unroll
        for (int nt = 0; nt < 4; nt++)
            acc[m0][nt] = (f32x4){0.f,0.f,0.f,0.f};

    for (int tap = 0; tap < 9; tap++){
        int dr = tap/3, dc = tap - 3*(tap/3);
        #pragma unroll
        for (int ks = 0; ks < 8; ks++){
            int ks72 = tap*8 + ks;
            const u16* bp = g_w2pk + (size_t)(ks72*32)*512;
            bf16x8 bh[4], bl[4];
            #pragma unroll
            for (int nt = 0; nt < 4; nt++){
                int ntg = wv*4 + nt;
                bh[nt] = *(const bf16x8*)(bp + ((size_t)ntg*64 + lane)*8);
                bl[nt] = *(const bf16x8*)(bp + ((size_t)(16 + ntg)*64 + lane)*8);
            }
            bf16x8 af[4];
            #pragma unroll
            for (int m0 = 0; m0 < 4; m0++){
                int L   = (m0*2 + rA + dr)*10 + cA + dc;
                int off = (L*512 + ks*64 + lg*16) ^ ((L & 7) << 4);
                af[m0]  = *(const bf16x8*)(sB + off);
            }
            #pragma unroll
            for (int m0 = 0; m0 < 4; m0++){
                #pragma unroll
                for (int nt = 0; nt < 4; nt++){
                    acc[m0][nt] = __builtin_amdgcn_mfma_f32_16x16x32_bf16(af[m0], bh[nt], acc[m0][nt], 0, 0, 0);
                    acc[m0][nt] = __builtin_amdgcn_mfma_f32_16x16x32_bf16(af[m0], bl[nt], acc[m0][nt], 0, 0, 0);
                }
            }
        }
    }

    // ---- epilogue: + per-pixel bias, relu, pack bf16, store [co][px] ----
    u16* dst = g_R0 + (size_t)b*C2_*64;
    #pragma unroll
    for (int m0 = 0; m0 < 4; m0++){
        int px0 = m0*16 + lg*4;
        #pragma unroll
        for (int nt = 0; nt < 4; nt++){
            int co = wv*64 + nt*16 + l15;
            float f0 = fmaxf(acc[m0][nt][0] + g_bias2p[(px0+0)*256 + co], 0.f);
            float f1 = fmaxf(acc[m0][nt][1] + g_bias2p[(px0+1)*256 + co], 0.f);
            float f2 = fmaxf(acc[m0][nt][2] + g_bias2p[(px0+2)*256 + co], 0.f);
            float f3 = fmaxf(acc[m0][nt][3] + g_bias2p[(px0+3)*256 + co], 0.f);
            uint2 o;
            o.x = (unsigned)f2u(f0) | ((unsigned)f2u(f1) << 16);
            o.y = (unsigned)f2u(f2) | ((unsigned)f2u(f3) << 16);
            *(uint2*)(dst + (size_t)co*64 + px0) = o;
        }
    }
}

// ---------------- conv3 weight prep: W3' = W3*sc2, hi/lo, fragment-packed --------------
__global__ __launch_bounds__(256) void k_prep_w3p(const float* __restrict__ w3){
    int id = blockIdx.x*256 + threadIdx.x;     // 32768 = 256 ci * 128 co
    if (id >= 32768) return;
    int co = id & 127, ci = id >> 7;
    float wv = w3[co*256 + ci] * g_stat[S_SC2 + ci];
    u16 hi = f2u(wv);
    u16 lo = f2u(wv - u2f(hi));
    int ks = ci >> 5, kin = ci & 31;
    int lanew = (kin >> 3)*16 + (co & 15);
    int j = kin & 7, ntg = co >> 4;
    size_t i0 = ((size_t)(ks*16 + ntg)*64 + lanew)*8 + j;
    g_w3pk[i0]        = hi;
    g_w3pk[i0 + 4096] = lo;
}
__global__ void k_prep_b3(const float* __restrict__ w3, const float* __restrict__ b3){
    int co = blockIdx.x;        // 128
    int ci = threadIdx.x;       // 256
    __shared__ float r[256];
    r[ci] = w3[co*256 + ci] * g_stat[S_SH2 + ci];
    __syncthreads();
    for (int off = 128; off > 0; off >>= 1){
        if (ci < off) r[ci] += r[ci + off];
        __syncthreads();
    }
    if (ci == 0) g_bias3p[co] = b3[co] + r[0];
}

// ---------------- stage 3 MFMA: 1x1 conv 256->128 (BN-2 folded) -> g_R1 raw ------------
__global__ __launch_bounds__(256) void k_conv3m(){
    __shared__ __align__(1024) u16 sA[16384];  // [64px][256ci] bf16, swizzled (32 KiB)
    char* sB = (char*)sA;
    int b = blockIdx.x;
    const u16* src = g_R0 + (size_t)b*C2_*64;
    for (int q = threadIdx.x; q < 1024; q += 256){
        int px0 = (q & 15)*4;
        int ci0 = (q >> 4)*4;
        ushort4 v0 = *(const ushort4*)(src + (ci0+0)*64 + px0);
        ushort4 v1 = *(const ushort4*)(src + (ci0+1)*64 + px0);
        ushort4 v2 = *(const ushort4*)(src + (ci0+2)*64 + px0);
        ushort4 v3 = *(const ushort4*)(src + (ci0+3)*64 + px0);
        #pragma unroll
        for (int i = 0; i < 4; i++){
            int px = px0 + i;
            int off = (px*512 + ci0*2) ^ ((px & 7) << 4);
            ushort4 w;
            w.x = (&v0.x)[i]; w.y = (&v1.x)[i]; w.z = (&v2.x)[i]; w.w = (&v3.x)[i];
            *(ushort4*)(sB + off) = w;
        }
    }
    __syncthreads();
    int lane = threadIdx.x & 63;
    int wv   = __builtin_amdgcn_readfirstlane(threadIdx.x >> 6);
    int l15  = lane & 15, lg = lane >> 4;
    f32x4 acc[4][2];
    #pragma unroll
    for (int m0 = 0; m0 < 4; m0++){ acc[m0][0] = (f32x4){0.f,0.f,0.f,0.f}; acc[m0][1] = (f32x4){0.f,0.f,0.f,0.f}; }
    #pragma unroll
    for (int ks = 0; ks < 8; ks++){
        bf16x8 bh[2], bl[2];
        #pragma unroll
        for (int nt = 0; nt < 2; nt++){
            int ntg = wv*2 + nt;
            const u16* bp = g_w3pk + ((size_t)(ks*16 + ntg)*64 + lane)*8;
            bh[nt] = *(const bf16x8*)bp;
            bl[nt] = *(const bf16x8*)(bp + 4096);
        }
        bf16x8 af[4];
        #pragma unroll
        for (int m0 = 0; m0 < 4; m0++){
            int px  = m0*16 + l15;
            int off = (px*512 + ks*64 + lg*16) ^ ((px & 7) << 4);
            af[m0]  = *(const bf16x8*)(sB + off);
        }
        #pragma unroll
        for (int m0 = 0; m0 < 4; m0++)
            #pragma unroll
            for (int nt = 0; nt < 2; nt++){
                acc[m0][nt] = __builtin_amdgcn_mfma_f32_16x16x32_bf16(af[m0], bh[nt], acc[m0][nt], 0, 0, 0);
                acc[m0][nt] = __builtin_amdgcn_mfma_f32_16x16x32_bf16(af[m0], bl[nt], acc[m0][nt], 0, 0, 0);
            }
    }
    u16* dst = g_R1 + (size_t)b*COUT_*64;
    #pragma unroll
    for (int m0 = 0; m0 < 4; m0++){
        int px0 = m0*16 + lg*4;
        #pragma unroll
        for (int nt = 0; nt < 2; nt++){
            int co = wv*32 + nt*16 + l15;
            float bb = g_bias3p[co];
            float f0 = fmaxf(acc[m0][nt][0] + bb, 0.f);
            float f1 = fmaxf(acc[m0][nt][1] + bb, 0.f);
            float f2 = fmaxf(acc[m0][nt][2] + bb, 0.f);
            float f3 = fmaxf(acc[m0][nt][3] + bb, 0.f);
            uint2 o;
            o.x = (unsigned)f2u(f0) | ((unsigned)f2u(f1) << 16);
            o.y = (unsigned)f2u(f2) | ((unsigned)f2u(f3) << 16);
            *(uint2*)(dst + (size_t)co*64 + px0) = o;
        }
    }
}

// ---------------- scatter: BN-3 + write active blocks into d_out (fp32), 8/thread ------
__global__ __launch_bounds__(256) void k_scatter(const int* __restrict__ abi,
                                                 float* __restrict__ out){
    int b  = blockIdx.x;
    int n  = abi[b*3+0], by = abi[b*3+1], bx = abi[b*3+2];
    float* base = out + (size_t)n*COUT_*HW_ + (size_t)(by*8)*W_ + bx*8;
    const u16* src = g_R1 + (size_t)b*COUT_*64;
    for (int t = threadIdx.x; t < 1024; t += 256){
        int co = t >> 3;
        int r  = t & 7;
        float sc = g_stat[S_SC3 + co], sh = g_stat[S_SH3 + co];
        uint4 v = *(const uint4*)(src + co*64 + r*8);
        float4 o0, o1;
        o0.x = sc*bitsf(v.x << 16)         + sh;
        o0.y = sc*bitsf(v.x & 0xffff0000u) + sh;
        o0.z = sc*bitsf(v.y << 16)         + sh;
        o0.w = sc*bitsf(v.y & 0xffff0000u) + sh;
        o1.x = sc*bitsf(v.z << 16)         + sh;
        o1.y = sc*bitsf(v.z & 0xffff0000u) + sh;
        o1.z = sc*bitsf(v.w << 16)         + sh;
        o1.w = sc*bitsf(v.w & 0xffff0000u) + sh;
        float* dst = base + (size_t)co*HW_ + r*W_;
        *(float4*)dst       = o0;
        *(float4*)(dst + 4) = o1;
    }
}

extern "C" void kernel_launch(void* const* d_in, const int* in_sizes, int n_in,
                              void* d_out, int out_size, void* d_ws, size_t ws_size,
                              hipStream_t stream){
    const float* x    = (const float*)d_in[0];
    const int*   abi  = (const int*)  d_in[1];
    const float* w_c  = (const float*)d_in[2];
    const float* b_c  = (const float*)d_in[3];
    const float* ga_c = (const float*)d_in[4];
    const float* be_c = (const float*)d_in[5];
    const float* w1   = (const float*)d_in[6];
    const float* b1   = (const float*)d_in[7];
    const float* ga1  = (const float*)d_in[8];
    const float* be1  = (const float*)d_in[9];
    const float* w2   = (const float*)d_in[10];
    const float* b2   = (const float*)d_in[11];
    const float* ga2  = (const float*)d_in[12];
    const float* be2  = (const float*)d_in[13];
    const float* w3   = (const float*)d_in[14];
    const float* b3   = (const float*)d_in[15];
    const float* ga3  = (const float*)d_in[16];
    const float* be3  = (const float*)d_in[17];
    int NB = in_sizes[1] / 3;              // 4096 active blocks
    (void)d_ws; (void)ws_size; (void)n_in; (void)out_size;

    k_zero<<<16, 256, 0, stream>>>();
    k_prep_weights<<<32, 256, 0, stream>>>(w_c);

    // stage A: conv -> raw (g_R0), stats, params, apply -> d_out (fp32 full image)
    k_convA<<<dim3(8192, 2), 256, 0, stream>>>(x, b_c);
    k_stats<<<128*8, 256, 0, stream>>>(0, 8, 128, 65536, 8, S_SUMA, S_SSA);
    k_params<<<1, 128, 0, stream>>>(S_SUMA, S_SSA, S_SCA, S_SHA, ga_c, be_c, 1.f/(8.f*65536.f), 128);
    k_apply_bn<<<32768, 256, 0, stream>>>((float*)d_out);   // must precede conv2m (g_R0 reuse)

    // stage 1: MFMA gather-conv (BN-A folded into W1), raw bf16 A-operand from g_R0
    k_prep_w1p<<<128, 256, 0, stream>>>(w1);
    k_prep_b1<<<256, 128, 0, stream>>>(w1, b1);
    k_conv1m<<<NB, 256, 0, stream>>>(abi);
    k_stats<<<256*32, 256, 0, stream>>>(1, NB, 256, 64, 32, S_SUM1, S_SS1);
    k_params<<<1, 256, 0, stream>>>(S_SUM1, S_SS1, S_SC1, S_SH1, ga1, be1, 1.f/((float)NB*64.f), 256);

    // conv2 weight/bias prep (needs sc1/sh1)
    k_prep_w2<<<2304, 256, 0, stream>>>(w2);
    k_prep_S2<<<2304, 256, 0, stream>>>(w2);
    k_prep_bias2<<<64, 256, 0, stream>>>(b2);

    // stage 2: 3x3 conv via MFMA, 2 blocks/workgroup -> raw (g_R0), stats, params
    k_conv2m<<<(NB + 1)/2, 512, 0, stream>>>(NB);
    k_stats<<<256*32, 256, 0, stream>>>(0, NB, 256, 64, 32, S_SUM2, S_SS2);
    k_params<<<1, 256, 0, stream>>>(S_SUM2, S_SS2, S_SC2, S_SH2, ga2, be2, 1.f/((float)NB*64.f), 256);

    // stage 3: MFMA 1x1 conv (BN-2 folded into W3) -> raw (g_R1), stats, params
    k_prep_w3p<<<128, 256, 0, stream>>>(w3);
    k_prep_b3<<<128, 256, 0, stream>>>(w3, b3);
    k_conv3m<<<NB, 256, 0, stream>>>();
    k_stats<<<128*32, 256, 0, stream>>>(1, NB, 128, 64, 32, S_SUM3, S_SS3);
    k_params<<<1, 128, 0, stream>>>(S_SUM3, S_SS3, S_SC3, S_SH3, ga3, be3, 1.f/((float)NB*64.f), 128);

    // scatter with BN-3
    k_scatter<<<NB, 256, 0, stream>>>(abi, (float*)d_out);
}